// Round 1
// baseline (948.747 us; speedup 1.0000x reference)
//
#include <hip/hip_runtime.h>
#include <cstdint>
#include <cstddef>

// MI355X MHA: S=1024 B=8 D=1024 H=16 dk=64.
// d_out = [ out (8,388,608 fp32) | attn (134,217,728 fp32) ]

typedef __attribute__((ext_vector_type(4))) float f32x4;
typedef __attribute__((ext_vector_type(8))) _Float16 half8;
typedef __attribute__((ext_vector_type(4))) _Float16 half4v;

typedef __attribute__((address_space(1))) unsigned int gu32;
typedef __attribute__((address_space(3))) unsigned int lu32;

#define MFMA16x16(A, B, C) __builtin_amdgcn_mfma_f32_16x16x32_f16((A), (B), (C), 0, 0, 0)
#define LOG2E 1.4426950408889634f
#define RSCALE 0.125f  // 1/sqrt(dk)=1/8

__device__ __forceinline__ void gl_lds16(const void* g, void* l) {
  // async global->LDS, 16B/lane; LDS dest = wave-uniform base + lane*16
  __builtin_amdgcn_global_load_lds(
      reinterpret_cast<gu32*>(reinterpret_cast<uintptr_t>(g)),
      reinterpret_cast<lu32*>((unsigned int)(uintptr_t)(l)),
      16, 0, 0);
}

__device__ __forceinline__ f32x4 fzero4() {
  f32x4 z; z[0] = 0.f; z[1] = 0.f; z[2] = 0.f; z[3] = 0.f; return z;
}

// ---------------------------------------------------------------- cast fp32->fp16
__global__ __launch_bounds__(256) void cast_all(
    const float* __restrict__ q, const float* __restrict__ k, const float* __restrict__ v,
    const float* __restrict__ wq, const float* __restrict__ wk, const float* __restrict__ wv,
    const float* __restrict__ wo,
    _Float16* __restrict__ oq, _Float16* __restrict__ ok, _Float16* __restrict__ ov,
    _Float16* __restrict__ owq, _Float16* __restrict__ owk, _Float16* __restrict__ owv,
    _Float16* __restrict__ owo) {
  int i = blockIdx.x * 256 + threadIdx.x;  // float4 index, exact: 7,340,032 total
  const float* src; _Float16* dst; int off;
  if (i < 2097152)      { src = q;  dst = oq;  off = i; }
  else if (i < 4194304) { src = k;  dst = ok;  off = i - 2097152; }
  else if (i < 6291456) { src = v;  dst = ov;  off = i - 4194304; }
  else if (i < 6553600) { src = wq; dst = owq; off = i - 6291456; }
  else if (i < 6815744) { src = wk; dst = owk; off = i - 6553600; }
  else if (i < 7077888) { src = wv; dst = owv; off = i - 6815744; }
  else                  { src = wo; dst = owo; off = i - 7077888; }
  float4 f = ((const float4*)src)[off];
  half4v o;
  o[0] = (_Float16)f.x; o[1] = (_Float16)f.y; o[2] = (_Float16)f.z; o[3] = (_Float16)f.w;
  *(half4v*)(dst + (size_t)off * 4) = o;
}

// ------------------------------------------------- QKV projection GEMM (z picks Q/K/V)
// C[t,e] = sum_d x[t,d]*w[e,d]; write f16 scattered to [B,H,S,dk]
__global__ __launch_bounds__(256) void proj_gemm(
    const _Float16* __restrict__ xq, const _Float16* __restrict__ xk, const _Float16* __restrict__ xv,
    const _Float16* __restrict__ wqm, const _Float16* __restrict__ wkm, const _Float16* __restrict__ wvm,
    _Float16* __restrict__ Qb, _Float16* __restrict__ Kb, _Float16* __restrict__ Vb) {
  __shared__ alignas(16) _Float16 lA[128 * 64];
  __shared__ alignas(16) _Float16 lB[128 * 64];

  const int z = blockIdx.z;
  const _Float16* A = (z == 0) ? xq : (z == 1) ? xk : xv;
  const _Float16* W = (z == 0) ? wqm : (z == 1) ? wkm : wvm;
  _Float16* O = (z == 0) ? Qb : (z == 1) ? Kb : Vb;

  const int m0 = blockIdx.x * 128, n0 = blockIdx.y * 128;
  const int tid = threadIdx.x;
  const int w = tid >> 6, ln = tid & 63;
  const int quad = ln >> 4, l15 = ln & 15;
  const int wm = w & 1, wn = w >> 1;

  f32x4 acc[4][4];
#pragma unroll
  for (int i = 0; i < 4; i++)
#pragma unroll
    for (int j = 0; j < 4; j++) acc[i][j] = fzero4();

  for (int k0 = 0; k0 < 1024; k0 += 64) {
    __syncthreads();
#pragma unroll
    for (int j = 0; j < 4; j++) {
      const int rb = w * 32 + j * 8;
      const int r = rb + (ln >> 3);
      const int g = (ln & 7) ^ (r & 7);  // XOR swizzle: slot c holds chunk c^(row&7)
      gl_lds16(A + (size_t)(m0 + r) * 1024 + k0 + g * 8, lA + rb * 64);
      gl_lds16(W + (size_t)(n0 + r) * 1024 + k0 + g * 8, lB + rb * 64);
    }
    __syncthreads();
#pragma unroll
    for (int ks = 0; ks < 2; ks++) {
      half8 af[4], bf[4];
#pragma unroll
      for (int mt = 0; mt < 4; mt++) {
        const int R = wm * 64 + mt * 16 + l15;
        const int slot = (ks * 4 + quad) ^ (R & 7);
        af[mt] = *(const half8*)((const char*)lA + R * 128 + slot * 16);
      }
#pragma unroll
      for (int nt = 0; nt < 4; nt++) {
        const int R = wn * 64 + nt * 16 + l15;
        const int slot = (ks * 4 + quad) ^ (R & 7);
        bf[nt] = *(const half8*)((const char*)lB + R * 128 + slot * 16);
      }
#pragma unroll
      for (int mt = 0; mt < 4; mt++)
#pragma unroll
        for (int nt = 0; nt < 4; nt++)
          acc[mt][nt] = MFMA16x16(af[mt], bf[nt], acc[mt][nt]);
    }
  }

#pragma unroll
  for (int mt = 0; mt < 4; mt++) {
    const int mb = m0 + wm * 64 + mt * 16 + quad * 4;  // D row = quad*4+reg
#pragma unroll
    for (int nt = 0; nt < 4; nt++) {
      const int n = n0 + wn * 64 + nt * 16 + l15;      // D col = lane&15
      const int h = n >> 6, i = n & 63;
#pragma unroll
      for (int r = 0; r < 4; r++) {
        const int m = mb + r;
        const int s = m >> 3, b = m & 7;               // t = s*8+b
        O[(size_t)((b * 16 + h) * 1024 + s) * 64 + i] = (_Float16)acc[mt][nt][r];
      }
    }
  }
}

// ------------------------------------------------- V [B,H,S,dk] -> Vt [B,H,dk,S]
__global__ __launch_bounds__(256) void v_transpose(const _Float16* __restrict__ V,
                                                   _Float16* __restrict__ Vt) {
  __shared__ _Float16 tile[64 * 72];
  const int bh = blockIdx.y, sblk = blockIdx.x;
  const int tid = threadIdx.x;
  const _Float16* src = V + (size_t)(bh * 1024 + sblk * 64) * 64;
#pragma unroll
  for (int j = 0; j < 2; j++) {
    int c = j * 256 + tid;
    int row = c >> 3, ch = c & 7;
    half8 x = *(const half8*)(src + row * 64 + ch * 8);
    union { half8 v; _Float16 e[8]; } u; u.v = x;
#pragma unroll
    for (int t2 = 0; t2 < 8; t2++) tile[row * 72 + ch * 8 + t2] = u.e[t2];
  }
  __syncthreads();
#pragma unroll
  for (int j = 0; j < 2; j++) {
    int c = j * 256 + tid;
    int i = c >> 3, sch = c & 7;
    union { half8 v; _Float16 e[8]; } o;
#pragma unroll
    for (int t2 = 0; t2 < 8; t2++) o.e[t2] = tile[(sch * 8 + t2) * 72 + i];
    *(half8*)(Vt + (size_t)(bh * 64 + i) * 1024 + sblk * 64 + sch * 8) = o.v;
  }
}

// ------------------------------------------------- fused attention
// grid (qblk=16, h=16, b=8); 256 thr = 4 waves; wave w owns q rows w*16..w*16+15
__global__ __launch_bounds__(256) void attn_kernel(
    const _Float16* __restrict__ Qb, const _Float16* __restrict__ Kb,
    const _Float16* __restrict__ Vt, const int* __restrict__ mask,
    float* __restrict__ attn, _Float16* __restrict__ ctx) {
  __shared__ alignas(16) _Float16 lQ[64 * 64];
  __shared__ alignas(16) _Float16 lK[64 * 64];
  __shared__ alignas(16) _Float16 lV[64 * 64];
  __shared__ alignas(16) _Float16 lP[4][16 * 72];
  __shared__ unsigned int lM[64 * 32];  // 64 rows x 1024 mask bits

  const int qblk = blockIdx.x, h = blockIdx.y, b = blockIdx.z;
  const int bh = b * 16 + h;
  const int tid = threadIdx.x, w = tid >> 6, ln = tid & 63;
  const int quad = ln >> 4, l15 = ln & 15;

  const _Float16* Qh = Qb + (size_t)(bh * 1024 + qblk * 64) * 64;
  const _Float16* Kh = Kb + (size_t)bh * 1024 * 64;
  const _Float16* Vh = Vt + (size_t)bh * 64 * 1024;
  float* attnp = attn + ((size_t)bh << 20) + (size_t)qblk * 64 * 1024;

  // stage Q block (swizzled), then lift per-wave A-fragments into registers
#pragma unroll
  for (int j = 0; j < 2; j++) {
    const int rb = w * 16 + j * 8;
    const int r = rb + (ln >> 3);
    const int g = (ln & 7) ^ (r & 7);
    gl_lds16(Qh + r * 64 + g * 8, lQ + rb * 64);
  }
  __syncthreads();
  half8 aq[2];
  {
    const int R = w * 16 + l15;
#pragma unroll
    for (int ks = 0; ks < 2; ks++) {
      const int slot = (ks * 4 + quad) ^ (R & 7);
      aq[ks] = *(const half8*)((const char*)lQ + R * 128 + slot * 16);
    }
  }

  float mrow[4], lrow[4];
#pragma unroll
  for (int r = 0; r < 4; r++) { mrow[r] = -3.0e38f; lrow[r] = 0.f; }

  // ---- pass 1: online (m,l) + build mask bitmask in LDS ----
  for (int t = 0; t < 16; t++) {
    __syncthreads();
#pragma unroll
    for (int j = 0; j < 2; j++) {
      const int rb = w * 16 + j * 8;
      const int r = rb + (ln >> 3);
      const int g = (ln & 7) ^ (r & 7);
      gl_lds16(Kh + (t * 64 + r) * 64 + g * 8, lK + rb * 64);
    }
    {  // mask tile -> bitmask (read mask from HBM exactly once)
      const int row = tid >> 2, cc = tid & 3;
      const int4* mp = (const int4*)(mask + ((size_t)b << 20) +
                                     (size_t)(qblk * 64 + row) * 1024 + t * 64 + cc * 16);
      unsigned int bits = 0;
#pragma unroll
      for (int u = 0; u < 4; u++) {
        int4 mv = mp[u];
        bits |= (unsigned)(mv.x != 0) << (u * 4 + 0);
        bits |= (unsigned)(mv.y != 0) << (u * 4 + 1);
        bits |= (unsigned)(mv.z != 0) << (u * 4 + 2);
        bits |= (unsigned)(mv.w != 0) << (u * 4 + 3);
      }
      ((unsigned short*)lM)[row * 64 + t * 4 + cc] = (unsigned short)bits;
    }
    __syncthreads();

    f32x4 sc[4];
#pragma unroll
    for (int nt = 0; nt < 4; nt++) sc[nt] = fzero4();
#pragma unroll
    for (int ks = 0; ks < 2; ks++) {
      half8 kf[4];
#pragma unroll
      for (int nt = 0; nt < 4; nt++) {
        const int R = nt * 16 + l15;
        const int slot = (ks * 4 + quad) ^ (R & 7);
        kf[nt] = *(const half8*)((const char*)lK + R * 128 + slot * 16);
      }
#pragma unroll
      for (int nt = 0; nt < 4; nt++) sc[nt] = MFMA16x16(aq[ks], kf[nt], sc[nt]);
    }
#pragma unroll
    for (int r = 0; r < 4; r++) {
      const int q = w * 16 + quad * 4 + r;
      const unsigned int w0 = lM[q * 32 + t * 2], w1 = lM[q * 32 + t * 2 + 1];
      float sv[4];
#pragma unroll
      for (int nt = 0; nt < 4; nt++) {
        float s = sc[nt][r] * RSCALE;
        const unsigned int word = (nt >= 2) ? w1 : w0;
        const unsigned int bit = (word >> ((nt & 1) * 16 + l15)) & 1u;
        sv[nt] = bit ? s : -1e9f;  // matches reference where(mask==0,-1e9)
      }
      float tm = fmaxf(fmaxf(sv[0], sv[1]), fmaxf(sv[2], sv[3]));
#pragma unroll
      for (int d = 1; d < 16; d <<= 1) tm = fmaxf(tm, __shfl_xor(tm, d));
      const float mnew = fmaxf(mrow[r], tm);
      float ts = exp2f((sv[0] - mnew) * LOG2E) + exp2f((sv[1] - mnew) * LOG2E) +
                 exp2f((sv[2] - mnew) * LOG2E) + exp2f((sv[3] - mnew) * LOG2E);
#pragma unroll
      for (int d = 1; d < 16; d <<= 1) ts += __shfl_xor(ts, d);
      lrow[r] = lrow[r] * exp2f((mrow[r] - mnew) * LOG2E) + ts;
      mrow[r] = mnew;
    }
  }

  float invl[4];
#pragma unroll
  for (int r = 0; r < 4; r++) invl[r] = 1.f / lrow[r];

  f32x4 co[4];
#pragma unroll
  for (int nt = 0; nt < 4; nt++) co[nt] = fzero4();

  // ---- pass 2: recompute scores, write attn, accumulate ctx ----
  for (int t = 0; t < 16; t++) {
    __syncthreads();
#pragma unroll
    for (int j = 0; j < 2; j++) {
      const int rb = w * 16 + j * 8;
      const int r = rb + (ln >> 3);
      const int g = (ln & 7) ^ (r & 7);
      gl_lds16(Kh + (t * 64 + r) * 64 + g * 8, lK + rb * 64);
      gl_lds16(Vh + r * 1024 + t * 64 + g * 8, lV + rb * 64);
    }
    __syncthreads();

    f32x4 sc[4];
#pragma unroll
    for (int nt = 0; nt < 4; nt++) sc[nt] = fzero4();
#pragma unroll
    for (int ks = 0; ks < 2; ks++) {
      half8 kf[4];
#pragma unroll
      for (int nt = 0; nt < 4; nt++) {
        const int R = nt * 16 + l15;
        const int slot = (ks * 4 + quad) ^ (R & 7);
        kf[nt] = *(const half8*)((const char*)lK + R * 128 + slot * 16);
      }
#pragma unroll
      for (int nt = 0; nt < 4; nt++) sc[nt] = MFMA16x16(aq[ks], kf[nt], sc[nt]);
    }

    _Float16* lPw = lP[w];
#pragma unroll
    for (int r = 0; r < 4; r++) {
      const int q = w * 16 + quad * 4 + r;
      const unsigned int w0 = lM[q * 32 + t * 2], w1 = lM[q * 32 + t * 2 + 1];
#pragma unroll
      for (int nt = 0; nt < 4; nt++) {
        float s = sc[nt][r] * RSCALE;
        const unsigned int word = (nt >= 2) ? w1 : w0;
        const unsigned int bit = (word >> ((nt & 1) * 16 + l15)) & 1u;
        s = bit ? s : -1e9f;
        const float p = exp2f((s - mrow[r]) * LOG2E) * invl[r];
        attnp[(size_t)q * 1024 + t * 64 + nt * 16 + l15] = p;  // normalized attn, fp32
        lPw[(quad * 4 + r) * 72 + nt * 16 + l15] = (_Float16)p;  // C-layout -> LDS
      }
    }
    asm volatile("s_waitcnt lgkmcnt(0)" ::: "memory");  // own-wave LDS round-trip

#pragma unroll
    for (int ks = 0; ks < 2; ks++) {
      const half8 pf = *(const half8*)((const char*)lP[w] + l15 * 144 + ks * 64 + quad * 16);
      half8 vf[4];
#pragma unroll
      for (int nt = 0; nt < 4; nt++) {
        const int R = nt * 16 + l15;
        const int slot = (ks * 4 + quad) ^ (R & 7);
        vf[nt] = *(const half8*)((const char*)lV + R * 128 + slot * 16);
      }
#pragma unroll
      for (int nt = 0; nt < 4; nt++) co[nt] = MFMA16x16(pf, vf[nt], co[nt]);
    }
  }

  // ctx -> [S,B,D] f16 for output projection
#pragma unroll
  for (int nt = 0; nt < 4; nt++) {
    const int i = nt * 16 + l15;
#pragma unroll
    for (int r = 0; r < 4; r++) {
      const int s = qblk * 64 + w * 16 + quad * 4 + r;
      ctx[(size_t)(s * 8 + b) * 1024 + h * 64 + i] = (_Float16)co[nt][r];
    }
  }
}

// ------------------------------------------------- output projection + bias (fp32 out)
__global__ __launch_bounds__(256) void out_gemm(
    const _Float16* __restrict__ A, const _Float16* __restrict__ W,
    const float* __restrict__ bias, float* __restrict__ out) {
  __shared__ alignas(16) _Float16 lA[128 * 64];
  __shared__ alignas(16) _Float16 lB[128 * 64];

  const int m0 = blockIdx.x * 128, n0 = blockIdx.y * 128;
  const int tid = threadIdx.x;
  const int w = tid >> 6, ln = tid & 63;
  const int quad = ln >> 4, l15 = ln & 15;
  const int wm = w & 1, wn = w >> 1;

  f32x4 acc[4][4];
#pragma unroll
  for (int i = 0; i < 4; i++)
#pragma unroll
    for (int j = 0; j < 4; j++) acc[i][j] = fzero4();

  for (int k0 = 0; k0 < 1024; k0 += 64) {
    __syncthreads();
#pragma unroll
    for (int j = 0; j < 4; j++) {
      const int rb = w * 32 + j * 8;
      const int r = rb + (ln >> 3);
      const int g = (ln & 7) ^ (r & 7);
      gl_lds16(A + (size_t)(m0 + r) * 1024 + k0 + g * 8, lA + rb * 64);
      gl_lds16(W + (size_t)(n0 + r) * 1024 + k0 + g * 8, lB + rb * 64);
    }
    __syncthreads();
#pragma unroll
    for (int ks = 0; ks < 2; ks++) {
      half8 af[4], bf[4];
#pragma unroll
      for (int mt = 0; mt < 4; mt++) {
        const int R = wm * 64 + mt * 16 + l15;
        const int slot = (ks * 4 + quad) ^ (R & 7);
        af[mt] = *(const half8*)((const char*)lA + R * 128 + slot * 16);
      }
#pragma unroll
      for (int nt = 0; nt < 4; nt++) {
        const int R = wn * 64 + nt * 16 + l15;
        const int slot = (ks * 4 + quad) ^ (R & 7);
        bf[nt] = *(const half8*)((const char*)lB + R * 128 + slot * 16);
      }
#pragma unroll
      for (int mt = 0; mt < 4; mt++)
#pragma unroll
        for (int nt = 0; nt < 4; nt++)
          acc[mt][nt] = MFMA16x16(af[mt], bf[nt], acc[mt][nt]);
    }
  }

#pragma unroll
  for (int nt = 0; nt < 4; nt++) {
    const int n = n0 + wn * 64 + nt * 16 + l15;
    const float bs = bias[n];
#pragma unroll
    for (int mt = 0; mt < 4; mt++) {
      const int mb = m0 + wm * 64 + mt * 16 + quad * 4;
#pragma unroll
      for (int r = 0; r < 4; r++)
        out[(size_t)(mb + r) * 1024 + n] = acc[mt][nt][r] + bs;
    }
  }
}

// ----------------------------------------------------------------------------
extern "C" void kernel_launch(void* const* d_in, const int* in_sizes, int n_in,
                              void* d_out, int out_size, void* d_ws, size_t ws_size,
                              hipStream_t stream) {
  const float* q  = (const float*)d_in[0];
  const float* k  = (const float*)d_in[1];
  const float* v  = (const float*)d_in[2];
  const int* mask = (const int*)d_in[3];
  const float* wq = (const float*)d_in[4];
  const float* wk = (const float*)d_in[5];
  const float* wv = (const float*)d_in[6];
  const float* wo = (const float*)d_in[7];
  const float* bo = (const float*)d_in[8];

  float* out  = (float*)d_out;                 // 8,388,608 fp32 [S,B,D]
  float* attn = (float*)d_out + 8388608;       // 134,217,728 fp32 [B,H,S,S]

  char* ws = (char*)d_ws;
  const size_t MB = 1024 * 1024;
  _Float16* xqb = (_Float16*)(ws + 0 * MB);    // 16 MB each
  _Float16* xkb = (_Float16*)(ws + 16 * MB);
  _Float16* xvb = (_Float16*)(ws + 32 * MB);
  _Float16* wqb = (_Float16*)(ws + 48 * MB);   // 2 MB each
  _Float16* wkb = (_Float16*)(ws + 50 * MB);
  _Float16* wvb = (_Float16*)(ws + 52 * MB);
  _Float16* wob = (_Float16*)(ws + 54 * MB);
  _Float16* Qb  = (_Float16*)(ws + 56 * MB);   // [B,H,S,dk] f16, 16 MB
  _Float16* Kb  = (_Float16*)(ws + 72 * MB);
  _Float16* Vb  = (_Float16*)(ws + 88 * MB);
  _Float16* Vtb = (_Float16*)(ws + 104 * MB);  // [B,H,dk,S]
  _Float16* ctx = (_Float16*)(ws + 0 * MB);    // reuse x region after proj_gemm

  cast_all<<<dim3(28672), dim3(256), 0, stream>>>(q, k, v, wq, wk, wv, wo,
                                                  xqb, xkb, xvb, wqb, wkb, wvb, wob);
  proj_gemm<<<dim3(64, 8, 3), dim3(256), 0, stream>>>(xqb, xkb, xvb, wqb, wkb, wvb,
                                                      Qb, Kb, Vb);
  v_transpose<<<dim3(16, 128), dim3(256), 0, stream>>>(Vb, Vtb);
  attn_kernel<<<dim3(16, 16, 8), dim3(256), 0, stream>>>(Qb, Kb, Vtb, mask, attn, ctx);
  out_gemm<<<dim3(64, 8), dim3(256), 0, stream>>>(ctx, wob, bo, out);
}